// Round 8
// baseline (178.439 us; speedup 1.0000x reference)
//
#include <hip/hip_runtime.h>
#include <hip/hip_bf16.h>

// Round 8: block-private partition — ZERO global atomics in the whole pipeline.
//
// Algebra (unchanged): voxel = c>>1, u = c&1:
//   norm_center = mu = sum(u)/count, variance = mu*(1-mu),
//   density = count / glob[batch].  Per segment need only packed
//   (count, sum_ux, sum_uy, sum_uz) in one u32.
//
// r7 evidence: partition with register-scatter is 42 us at 1.27 TB/s, 52% occ,
// 6% VALU -> serialization, and the only deep-serial primitive left was the
// per-bucket global cursor reservation (125K device atomics, 489-deep chains
// on 256 hot addresses, all blocks co-resident). Fix: block-major payload
// layout payload[blk*PTS + local_off] -- offsets are implicit, no reservation.
// Per-block bucket bases (LDS shfl-scan, 2 barriers) go to a global table;
// pass 2 walks per-bucket chunk lists; a tiny kernel derives glob[4].

#define BLOCK1 1024          // partition threads/block
#define PPT 8                // points per thread
#define PTS (BLOCK1 * PPT)   // 8192 points per block
#define BUCKETS 256
#define SEG_SHIFT 12         // log2(SPB)
#define SPB 4096             // segments per bucket; S = BUCKETS*SPB = 2^20
#define BLOCK2 512           // stats threads/block (>= NBLK=489 for 1 chunk/thread)
#define FBLOCK 256           // fallback path block size

__device__ __forceinline__ unsigned make_pay(int b, int x, int y, int z, int gs) {
    const int seg = (((b * gs + (x >> 1)) * gs + (y >> 1)) * gs) + (z >> 1);
    return ((unsigned)seg << 3) | ((unsigned)(x & 1) << 2)
         | ((unsigned)(y & 1) << 1) | (unsigned)(z & 1);
}

// ---------------- pass 1: block-private bucket partition ----------------
__global__ __launch_bounds__(BLOCK1, 2)
void partition_kernel(const int* __restrict__ bidx,
                      const int* __restrict__ coords,
                      const int* __restrict__ gptr,
                      unsigned* __restrict__ payload,  // [NBLK * PTS] block-major
                      unsigned* __restrict__ bases,    // [NBLK * BUCKETS]
                      int N) {
    __shared__ unsigned s_hist[BUCKETS];
    __shared__ unsigned s_base[BUCKETS];   // in-block exclusive offsets
    __shared__ unsigned s_cur[BUCKETS];    // in-block rank cursors
    __shared__ unsigned s_wsum[4];         // per-wave scan totals

    const int tid = threadIdx.x;
    if (tid < BUCKETS) { s_hist[tid] = 0u; s_cur[tid] = 0u; }
    __syncthreads();

    const int gs = gptr[0] >> 1;           // output grid extent (64)
    const int base = blockIdx.x * PTS;

    const int4* __restrict__ bidx4 = (const int4*)bidx;
    const int4* __restrict__ crd4  = (const int4*)coords;

    // ---- phase A: load 8 points/thread into registers, LDS histogram.
    // Valid payloads are < 2^23, so 0xFFFFFFFF is a safe tail sentinel.
    unsigned pay[PPT];
    #pragma unroll
    for (int g = 0; g < PPT / 4; ++g) {
        const int p0 = base + (g * BLOCK1 + tid) * 4;
        if (p0 + 3 < N) {
            const int q = p0 >> 2;
            const int4 b4 = bidx4[q];
            const int4 c0 = crd4[3 * q + 0];
            const int4 c1 = crd4[3 * q + 1];
            const int4 c2 = crd4[3 * q + 2];
            pay[g * 4 + 0] = make_pay(b4.x, c0.x, c0.y, c0.z, gs);
            pay[g * 4 + 1] = make_pay(b4.y, c0.w, c1.x, c1.y, gs);
            pay[g * 4 + 2] = make_pay(b4.z, c1.z, c1.w, c2.x, gs);
            pay[g * 4 + 3] = make_pay(b4.w, c2.y, c2.z, c2.w, gs);
        } else {
            #pragma unroll
            for (int j = 0; j < 4; ++j) {
                const int p = p0 + j;
                pay[g * 4 + j] = (p < N)
                    ? make_pay(bidx[p], coords[3 * p + 0],
                               coords[3 * p + 1], coords[3 * p + 2], gs)
                    : 0xFFFFFFFFu;
            }
        }
    }
    #pragma unroll
    for (int j = 0; j < PPT; ++j)
        if (pay[j] != 0xFFFFFFFFu)
            atomicAdd(&s_hist[pay[j] >> (SEG_SHIFT + 3)], 1u);
    __syncthreads();

    // ---- phase B: exclusive scan of 256 counts, NO global atomics.
    // Waves 0-3 each shfl-scan 64 entries; 2 barriers total.
    unsigned v = 0u, incl = 0u;
    if (tid < BUCKETS) {
        v = s_hist[tid];
        incl = v;
        #pragma unroll
        for (int d = 1; d < 64; d <<= 1) {
            const unsigned t = __shfl_up(incl, d, 64);
            if ((tid & 63) >= d) incl += t;
        }
        if ((tid & 63) == 63) s_wsum[tid >> 6] = incl;
    }
    __syncthreads();
    if (tid < BUCKETS) {
        const int w = tid >> 6;
        unsigned off = 0u;
        if (w > 0) off += s_wsum[0];
        if (w > 1) off += s_wsum[1];
        if (w > 2) off += s_wsum[2];
        const unsigned ex = incl - v + off;
        s_base[tid] = ex;
        bases[(size_t)blockIdx.x * BUCKETS + tid] = ex;  // coalesced 1 KB
    }
    __syncthreads();

    // ---- phase C: scatter from registers into the block's PRIVATE region.
    // Offsets are provably < block's valid count <= PTS (rank < hist count).
    #pragma unroll
    for (int j = 0; j < PPT; ++j) {
        const unsigned p = pay[j];
        if (p != 0xFFFFFFFFu) {
            const unsigned bk = p >> (SEG_SHIFT + 3);
            const unsigned r = atomicAdd(&s_cur[bk], 1u);
            payload[(size_t)base + s_base[bk] + r] = p;
        }
    }
}

// ---- tiny kernel: glob[batch] = total points per batch, from bases table ----
__global__ __launch_bounds__(256)
void glob_kernel(const unsigned* __restrict__ bases,
                 unsigned* __restrict__ glob, int NBLK, int N) {
    __shared__ unsigned gl[4];
    const int tid = threadIdx.x;
    if (tid < 4) gl[tid] = 0u;
    __syncthreads();
    unsigned g0 = 0, g1 = 0, g2 = 0, g3 = 0;
    for (int blk = tid; blk < NBLK; blk += 256) {
        const size_t o = (size_t)blk * BUCKETS;
        const unsigned b64  = bases[o + 64];
        const unsigned b128 = bases[o + 128];
        const unsigned b192 = bases[o + 192];
        const unsigned bend = (unsigned)min(PTS, N - blk * PTS);
        g0 += b64;          // bases[o+0] == 0 (exclusive scan)
        g1 += b128 - b64;
        g2 += b192 - b128;
        g3 += bend - b192;
    }
    atomicAdd(&gl[0], g0);
    atomicAdd(&gl[1], g1);
    atomicAdd(&gl[2], g2);
    atomicAdd(&gl[3], g3);
    __syncthreads();
    if (tid < 4) glob[tid] = gl[tid];
}

// -------- pass 2: per-bucket LDS accumulation + fused finalize --------
__global__ __launch_bounds__(BLOCK2)
void stats_kernel(const unsigned* __restrict__ payload,
                  const unsigned* __restrict__ bases,
                  const unsigned* __restrict__ glob,
                  float* __restrict__ out, int NBLK, int N) {
    __shared__ unsigned fine[SPB];        // 16 KB packed (count,ux,uy,uz)
    __shared__ float s_stage[BLOCK2 * 7]; // 14 KB row staging for coalesced out

    const int tid = threadIdx.x;
    const int k = blockIdx.x;

    for (int s = tid; s < SPB; s += BLOCK2) fine[s] = 0u;
    __syncthreads();

    // walk this bucket's chunk in every block's private region
    for (int blk = tid; blk < NBLK; blk += BLOCK2) {
        const size_t o = (size_t)blk * BUCKETS;
        const unsigned s = bases[o + k];
        const unsigned e = (k < BUCKETS - 1) ? bases[o + k + 1]
                                             : (unsigned)min(PTS, N - blk * PTS);
        const unsigned* __restrict__ pp = payload + (size_t)blk * PTS;
        for (unsigned j = s; j < e; ++j) {
            const unsigned p = pp[j];
            atomicAdd(&fine[(p >> 3) & (SPB - 1)],
                      (1u << 24) | ((p & 4u) << 14) | ((p & 2u) << 7) | (p & 1u));
        }
    }
    __syncthreads();

    const float ginv = 1.0f / (float)glob[k >> 6];  // 64 buckets per batch

    // finalize in 8 tiles of 512 rows: compute -> LDS stage -> float4 out
    for (int t = 0; t < SPB; t += BLOCK2) {
        const unsigned a = fine[t + tid];
        const int c = (int)(a >> 24);
        float d0 = 0.f, vx = 0.f, vy = 0.f, vz = 0.f, mx = 0.f, my = 0.f, mz = 0.f;
        if (c > 0) {
            const float inv = 1.0f / (float)c;
            mx = (float)((a >> 16) & 0xffu) * inv;
            my = (float)((a >> 8) & 0xffu) * inv;
            mz = (float)(a & 0xffu) * inv;
            vx = mx - mx * mx;
            vy = my - my * my;
            vz = mz - mz * mz;
            d0 = (float)c * ginv;
        }
        float* st = &s_stage[tid * 7];
        st[0] = d0;
        st[1] = vx; st[2] = vy; st[3] = vz;
        st[4] = mx; st[5] = my; st[6] = mz;
        __syncthreads();

        const float4* src = (const float4*)s_stage;
        float4* dst = (float4*)(out + ((size_t)k * SPB + t) * 7);
        #pragma unroll
        for (int j = 0; j < 2; ++j) {
            const int idx = j * BLOCK2 + tid;
            if (idx < (BLOCK2 * 7) / 4) dst[idx] = src[idx];
        }
        __syncthreads();
    }
}

// ---------------- fallback (round-2 path, known-good) ----------------
__global__ __launch_bounds__(FBLOCK)
void accum_kernel(const int* __restrict__ bidx,
                  const int* __restrict__ coords,
                  const int* __restrict__ gptr,
                  unsigned* __restrict__ acc, int astride,
                  int* __restrict__ glob, int N) {
    __shared__ int gcnt[4];
    if (threadIdx.x < 4) gcnt[threadIdx.x] = 0;
    __syncthreads();
    const int gs = gptr[0] >> 1;
    int l0 = 0, l1 = 0, l2 = 0, l3 = 0;
    const int stride = gridDim.x * blockDim.x;
    for (int i = blockIdx.x * blockDim.x + threadIdx.x; i < N; i += stride) {
        const int b  = bidx[i];
        const int cx = coords[3 * i + 0];
        const int cy = coords[3 * i + 1];
        const int cz = coords[3 * i + 2];
        const int seg = (((b * gs + (cx >> 1)) * gs + (cy >> 1)) * gs) + (cz >> 1);
        const unsigned val = (1u << 24)
                           | ((unsigned)(cx & 1) << 16)
                           | ((unsigned)(cy & 1) << 8)
                           |  (unsigned)(cz & 1);
        atomicAdd(&acc[(size_t)seg * astride], val);
        l0 += (b == 0); l1 += (b == 1); l2 += (b == 2); l3 += (b == 3);
    }
    if (l0) atomicAdd(&gcnt[0], l0);
    if (l1) atomicAdd(&gcnt[1], l1);
    if (l2) atomicAdd(&gcnt[2], l2);
    if (l3) atomicAdd(&gcnt[3], l3);
    __syncthreads();
    if (threadIdx.x < 4 && gcnt[threadIdx.x] != 0)
        atomicAdd(&glob[threadIdx.x], gcnt[threadIdx.x]);
}

__global__ __launch_bounds__(FBLOCK)
void finalize_kernel(const unsigned* __restrict__ acc, int astride,
                     const int* __restrict__ glob,
                     float* __restrict__ out, int S, int pbShift) {
    const int s = blockIdx.x * blockDim.x + threadIdx.x;
    if (s >= S) return;
    const unsigned a = acc[(size_t)s * astride];
    const int b = s >> pbShift;
    const int c = (int)(a >> 24);
    float d0 = 0.f, vx = 0.f, vy = 0.f, vz = 0.f, mx = 0.f, my = 0.f, mz = 0.f;
    if (c > 0) {
        const float inv = 1.0f / (float)c;
        mx = (float)((a >> 16) & 0xffu) * inv;
        my = (float)((a >> 8) & 0xffu) * inv;
        mz = (float)(a & 0xffu) * inv;
        vx = mx - mx * mx; vy = my - my * my; vz = mz - mz * mz;
        d0 = (float)c / (float)glob[b];
    }
    float* row = out + (size_t)s * 7;
    row[0] = d0;
    row[1] = vx; row[2] = vy; row[3] = vz;
    row[4] = mx; row[5] = my; row[6] = mz;
}

extern "C" void kernel_launch(void* const* d_in, const int* in_sizes, int n_in,
                              void* d_out, int out_size, void* d_ws, size_t ws_size,
                              hipStream_t stream) {
    const int* bidx   = (const int*)d_in[1];   // batch_idx [N]
    const int* coords = (const int*)d_in[2];   // coords [N,3]
    const int* gptr   = (const int*)d_in[3];   // grid_size scalar (128)

    const int N = in_sizes[1];
    const int S = out_size / 7;                // 1,048,576
    const int per_batch = S / 4;               // B = 4

    const int NBLK = (N + PTS - 1) / PTS;      // 489
    // ws layout: glob[4] @0 | bases @1024 | payload @payOff (block-major)
    const size_t basesBytes = (size_t)NBLK * BUCKETS * 4u;
    const size_t payOff = (1024 + basesBytes + 4095) & ~(size_t)4095;
    const size_t need = payOff + (size_t)NBLK * PTS * 4u;   // ~16.6 MB

    const bool fast = (S == (BUCKETS * SPB)) && (per_batch / SPB == 64) &&
                      (ws_size >= need) && (N > 0) && (NBLK <= BLOCK2);

    if (fast) {
        unsigned* glob    = (unsigned*)d_ws;
        unsigned* bases   = (unsigned*)((char*)d_ws + 1024);
        unsigned* payload = (unsigned*)((char*)d_ws + payOff);
        // no memsets: every byte consumed is rewritten every call

        partition_kernel<<<NBLK, BLOCK1, 0, stream>>>(
            bidx, coords, gptr, payload, bases, N);
        glob_kernel<<<1, 256, 0, stream>>>(bases, glob, NBLK, N);
        stats_kernel<<<BUCKETS, BLOCK2, 0, stream>>>(
            payload, bases, glob, (float*)d_out, NBLK, N);
    } else {
        // known-good round-2 path
        int pbShift = 0;
        while ((1 << pbShift) < per_batch) ++pbShift;
        int* glob = (int*)d_ws;
        const size_t accBytes = (size_t)S * sizeof(unsigned);
        unsigned* acc;
        int astride;
        if (ws_size >= accBytes + 64) {
            acc = (unsigned*)((char*)d_ws + 64);
            astride = 1;
            hipMemsetAsync(d_ws, 0, 64 + accBytes, stream);
        } else {
            acc = (unsigned*)d_out;
            astride = 7;
            hipMemsetAsync(d_out, 0, (size_t)out_size * sizeof(float), stream);
            hipMemsetAsync(d_ws, 0, 64, stream);
        }
        int accBlocks = (N + FBLOCK - 1) / FBLOCK;
        if (accBlocks > 2048) accBlocks = 2048;
        accum_kernel<<<accBlocks, FBLOCK, 0, stream>>>(bidx, coords, gptr,
                                                       acc, astride, glob, N);
        const int finBlocks = (S + FBLOCK - 1) / FBLOCK;
        finalize_kernel<<<finBlocks, FBLOCK, 0, stream>>>(acc, astride, glob,
                                                          (float*)d_out, S, pbShift);
    }
}

// Round 9
// 167.567 us; speedup vs baseline: 1.0649x; 1.0649x over previous
//
#include <hip/hip_runtime.h>
#include <hip/hip_bf16.h>

// Round 9: reservation-free block-private partition (r8) + chunk geometry
// fixed so pass 2 is wave-coalesced again.
//
// Algebra (unchanged): voxel = c>>1, u = c&1:
//   norm_center = mu = sum(u)/count, variance = mu*(1-mu),
//   density = count / glob[batch].  Per segment need only packed
//   (count, sum_ux, sum_uy, sum_uz) in one u32.
//
// r8 evidence: block-private payload killed stats locality (489 chunks of
// ~17 elems/bucket; one-chunk-per-thread -> 64 scattered lines per wave
// load). Fix: PTS=16384 -> 245 chunks of ~64 elems (= one wave-wide
// coalesced read); stats assigns one WAVE per chunk. Partition keeps
// zero global atomics: register scatter into private window, shfl-scan
// bases table, tiny glob kernel derives per-batch totals.

#define BLOCK1 1024          // partition threads/block
#define PPT 16               // points per thread
#define PTS (BLOCK1 * PPT)   // 16384 points per block
#define BUCKETS 256
#define SEG_SHIFT 12         // log2(SPB)
#define SPB 4096             // segments per bucket; S = BUCKETS*SPB = 2^20
#define BLOCK2 1024          // stats threads/block (16 waves)
#define MAXBLK 512           // stats LDS range-table capacity
#define FBLOCK 256           // fallback path block size

__device__ __forceinline__ unsigned make_pay(int b, int x, int y, int z, int gs) {
    const int seg = (((b * gs + (x >> 1)) * gs + (y >> 1)) * gs) + (z >> 1);
    return ((unsigned)seg << 3) | ((unsigned)(x & 1) << 2)
         | ((unsigned)(y & 1) << 1) | (unsigned)(z & 1);
}

// ---------------- pass 1: block-private bucket partition ----------------
__global__ __launch_bounds__(BLOCK1, 4)
void partition_kernel(const int* __restrict__ bidx,
                      const int* __restrict__ coords,
                      const int* __restrict__ gptr,
                      unsigned* __restrict__ payload,  // [NBLK * PTS] block-major
                      unsigned* __restrict__ bases,    // [NBLK * BUCKETS]
                      int N) {
    __shared__ unsigned s_hist[BUCKETS];
    __shared__ unsigned s_base[BUCKETS];   // in-block exclusive offsets
    __shared__ unsigned s_cur[BUCKETS];    // in-block rank cursors
    __shared__ unsigned s_wsum[4];         // per-wave scan totals

    const int tid = threadIdx.x;
    if (tid < BUCKETS) { s_hist[tid] = 0u; s_cur[tid] = 0u; }
    __syncthreads();

    const int gs = gptr[0] >> 1;           // output grid extent (64)
    const int base = blockIdx.x * PTS;

    const int4* __restrict__ bidx4 = (const int4*)bidx;
    const int4* __restrict__ crd4  = (const int4*)coords;

    // ---- phase A: load 16 points/thread into registers, LDS histogram.
    // Valid payloads are < 2^23, so 0xFFFFFFFF is a safe tail sentinel.
    unsigned pay[PPT];
    #pragma unroll
    for (int g = 0; g < PPT / 4; ++g) {
        const int p0 = base + (g * BLOCK1 + tid) * 4;
        if (p0 + 3 < N) {
            const int q = p0 >> 2;
            const int4 b4 = bidx4[q];
            const int4 c0 = crd4[3 * q + 0];
            const int4 c1 = crd4[3 * q + 1];
            const int4 c2 = crd4[3 * q + 2];
            pay[g * 4 + 0] = make_pay(b4.x, c0.x, c0.y, c0.z, gs);
            pay[g * 4 + 1] = make_pay(b4.y, c0.w, c1.x, c1.y, gs);
            pay[g * 4 + 2] = make_pay(b4.z, c1.z, c1.w, c2.x, gs);
            pay[g * 4 + 3] = make_pay(b4.w, c2.y, c2.z, c2.w, gs);
        } else {
            #pragma unroll
            for (int j = 0; j < 4; ++j) {
                const int p = p0 + j;
                pay[g * 4 + j] = (p < N)
                    ? make_pay(bidx[p], coords[3 * p + 0],
                               coords[3 * p + 1], coords[3 * p + 2], gs)
                    : 0xFFFFFFFFu;
            }
        }
    }
    #pragma unroll
    for (int j = 0; j < PPT; ++j)
        if (pay[j] != 0xFFFFFFFFu)
            atomicAdd(&s_hist[pay[j] >> (SEG_SHIFT + 3)], 1u);
    __syncthreads();

    // ---- phase B: exclusive scan of 256 counts (shfl, 2 barriers),
    // write this block's bases row (coalesced 1 KB). No global atomics.
    unsigned v = 0u, incl = 0u;
    if (tid < BUCKETS) {
        v = s_hist[tid];
        incl = v;
        #pragma unroll
        for (int d = 1; d < 64; d <<= 1) {
            const unsigned t = __shfl_up(incl, d, 64);
            if ((tid & 63) >= d) incl += t;
        }
        if ((tid & 63) == 63) s_wsum[tid >> 6] = incl;
    }
    __syncthreads();
    if (tid < BUCKETS) {
        const int w = tid >> 6;
        unsigned off = 0u;
        if (w > 0) off += s_wsum[0];
        if (w > 1) off += s_wsum[1];
        if (w > 2) off += s_wsum[2];
        const unsigned ex = incl - v + off;
        s_base[tid] = ex;
        bases[(size_t)blockIdx.x * BUCKETS + tid] = ex;
    }
    __syncthreads();

    // ---- phase C: scatter from registers into the block's PRIVATE 64 KB
    // window; per-bucket runs ~256 B contiguous (write-combining friendly).
    // Offsets provably < block valid count <= PTS.
    #pragma unroll
    for (int j = 0; j < PPT; ++j) {
        const unsigned p = pay[j];
        if (p != 0xFFFFFFFFu) {
            const unsigned bk = p >> (SEG_SHIFT + 3);
            const unsigned r = atomicAdd(&s_cur[bk], 1u);
            payload[(size_t)base + s_base[bk] + r] = p;
        }
    }
}

// ---- tiny kernel: glob[batch] = points per batch, from bases table ----
__global__ __launch_bounds__(256)
void glob_kernel(const unsigned* __restrict__ bases,
                 unsigned* __restrict__ glob, int NBLK, int N) {
    __shared__ unsigned gl[4];
    const int tid = threadIdx.x;
    if (tid < 4) gl[tid] = 0u;
    __syncthreads();
    unsigned g0 = 0, g1 = 0, g2 = 0, g3 = 0;
    for (int blk = tid; blk < NBLK; blk += 256) {
        const size_t o = (size_t)blk * BUCKETS;
        const unsigned b64  = bases[o + 64];
        const unsigned b128 = bases[o + 128];
        const unsigned b192 = bases[o + 192];
        const unsigned bend = (unsigned)min(PTS, N - blk * PTS);
        g0 += b64;          // bases[o+0] == 0 (exclusive scan)
        g1 += b128 - b64;
        g2 += b192 - b128;
        g3 += bend - b192;
    }
    atomicAdd(&gl[0], g0);
    atomicAdd(&gl[1], g1);
    atomicAdd(&gl[2], g2);
    atomicAdd(&gl[3], g3);
    __syncthreads();
    if (tid < 4) glob[tid] = gl[tid];
}

// -------- pass 2: per-bucket LDS accumulation + fused finalize --------
// One WAVE per ~64-element chunk: coalesced contiguous reads.
__global__ __launch_bounds__(BLOCK2)
void stats_kernel(const unsigned* __restrict__ payload,
                  const unsigned* __restrict__ bases,
                  const unsigned* __restrict__ glob,
                  float* __restrict__ out, int NBLK, int N) {
    __shared__ unsigned fine[SPB];          // 16 KB packed (count,ux,uy,uz)
    __shared__ float s_stage[BLOCK2 * 7];   // 28 KB row staging
    __shared__ unsigned s_s[MAXBLK];        // chunk starts
    __shared__ unsigned s_e[MAXBLK];        // chunk ends

    const int tid = threadIdx.x;
    const int k = blockIdx.x;

    for (int s = tid; s < SPB; s += BLOCK2) fine[s] = 0u;
    for (int blk = tid; blk < NBLK; blk += BLOCK2) {
        const size_t o = (size_t)blk * BUCKETS;
        s_s[blk] = bases[o + k];
        s_e[blk] = (k < BUCKETS - 1) ? bases[o + k + 1]
                                     : (unsigned)min(PTS, N - blk * PTS);
    }
    __syncthreads();

    const int wave = tid >> 6, lane = tid & 63, nw = BLOCK2 / 64;
    for (int blk = wave; blk < NBLK; blk += nw) {
        const unsigned s = s_s[blk], e = s_e[blk];
        const unsigned* __restrict__ pp = payload + (size_t)blk * PTS;
        for (unsigned j = s + lane; j < e; j += 64) {
            const unsigned p = pp[j];
            atomicAdd(&fine[(p >> 3) & (SPB - 1)],
                      (1u << 24) | ((p & 4u) << 14) | ((p & 2u) << 7) | (p & 1u));
        }
    }
    __syncthreads();

    const float ginv = 1.0f / (float)glob[k >> 6];  // 64 buckets per batch

    // finalize in 4 tiles of 1024 rows: compute -> LDS stage -> float4 out
    for (int t = 0; t < SPB; t += BLOCK2) {
        const unsigned a = fine[t + tid];
        const int c = (int)(a >> 24);
        float d0 = 0.f, vx = 0.f, vy = 0.f, vz = 0.f, mx = 0.f, my = 0.f, mz = 0.f;
        if (c > 0) {
            const float inv = 1.0f / (float)c;
            mx = (float)((a >> 16) & 0xffu) * inv;
            my = (float)((a >> 8) & 0xffu) * inv;
            mz = (float)(a & 0xffu) * inv;
            vx = mx - mx * mx;
            vy = my - my * my;
            vz = mz - mz * mz;
            d0 = (float)c * ginv;
        }
        float* st = &s_stage[tid * 7];
        st[0] = d0;
        st[1] = vx; st[2] = vy; st[3] = vz;
        st[4] = mx; st[5] = my; st[6] = mz;
        __syncthreads();

        const float4* src = (const float4*)s_stage;
        float4* dst = (float4*)(out + ((size_t)k * SPB + t) * 7);
        #pragma unroll
        for (int j = 0; j < 2; ++j) {
            const int idx = j * BLOCK2 + tid;
            if (idx < (BLOCK2 * 7) / 4) dst[idx] = src[idx];
        }
        __syncthreads();
    }
}

// ---------------- fallback (round-2 path, known-good) ----------------
__global__ __launch_bounds__(FBLOCK)
void accum_kernel(const int* __restrict__ bidx,
                  const int* __restrict__ coords,
                  const int* __restrict__ gptr,
                  unsigned* __restrict__ acc, int astride,
                  int* __restrict__ glob, int N) {
    __shared__ int gcnt[4];
    if (threadIdx.x < 4) gcnt[threadIdx.x] = 0;
    __syncthreads();
    const int gs = gptr[0] >> 1;
    int l0 = 0, l1 = 0, l2 = 0, l3 = 0;
    const int stride = gridDim.x * blockDim.x;
    for (int i = blockIdx.x * blockDim.x + threadIdx.x; i < N; i += stride) {
        const int b  = bidx[i];
        const int cx = coords[3 * i + 0];
        const int cy = coords[3 * i + 1];
        const int cz = coords[3 * i + 2];
        const int seg = (((b * gs + (cx >> 1)) * gs + (cy >> 1)) * gs) + (cz >> 1);
        const unsigned val = (1u << 24)
                           | ((unsigned)(cx & 1) << 16)
                           | ((unsigned)(cy & 1) << 8)
                           |  (unsigned)(cz & 1);
        atomicAdd(&acc[(size_t)seg * astride], val);
        l0 += (b == 0); l1 += (b == 1); l2 += (b == 2); l3 += (b == 3);
    }
    if (l0) atomicAdd(&gcnt[0], l0);
    if (l1) atomicAdd(&gcnt[1], l1);
    if (l2) atomicAdd(&gcnt[2], l2);
    if (l3) atomicAdd(&gcnt[3], l3);
    __syncthreads();
    if (threadIdx.x < 4 && gcnt[threadIdx.x] != 0)
        atomicAdd(&glob[threadIdx.x], gcnt[threadIdx.x]);
}

__global__ __launch_bounds__(FBLOCK)
void finalize_kernel(const unsigned* __restrict__ acc, int astride,
                     const int* __restrict__ glob,
                     float* __restrict__ out, int S, int pbShift) {
    const int s = blockIdx.x * blockDim.x + threadIdx.x;
    if (s >= S) return;
    const unsigned a = acc[(size_t)s * astride];
    const int b = s >> pbShift;
    const int c = (int)(a >> 24);
    float d0 = 0.f, vx = 0.f, vy = 0.f, vz = 0.f, mx = 0.f, my = 0.f, mz = 0.f;
    if (c > 0) {
        const float inv = 1.0f / (float)c;
        mx = (float)((a >> 16) & 0xffu) * inv;
        my = (float)((a >> 8) & 0xffu) * inv;
        mz = (float)(a & 0xffu) * inv;
        vx = mx - mx * mx; vy = my - my * my; vz = mz - mz * mz;
        d0 = (float)c / (float)glob[b];
    }
    float* row = out + (size_t)s * 7;
    row[0] = d0;
    row[1] = vx; row[2] = vy; row[3] = vz;
    row[4] = mx; row[5] = my; row[6] = mz;
}

extern "C" void kernel_launch(void* const* d_in, const int* in_sizes, int n_in,
                              void* d_out, int out_size, void* d_ws, size_t ws_size,
                              hipStream_t stream) {
    const int* bidx   = (const int*)d_in[1];   // batch_idx [N]
    const int* coords = (const int*)d_in[2];   // coords [N,3]
    const int* gptr   = (const int*)d_in[3];   // grid_size scalar (128)

    const int N = in_sizes[1];
    const int S = out_size / 7;                // 1,048,576
    const int per_batch = S / 4;               // B = 4

    const int NBLK = (N + PTS - 1) / PTS;      // 245
    // ws layout: glob[4] @0 | bases @1024 | payload @payOff (block-major)
    const size_t basesBytes = (size_t)NBLK * BUCKETS * 4u;
    const size_t payOff = (1024 + basesBytes + 4095) & ~(size_t)4095;
    const size_t need = payOff + (size_t)NBLK * PTS * 4u;   // ~16.3 MB

    const bool fast = (S == (BUCKETS * SPB)) && (per_batch / SPB == 64) &&
                      (ws_size >= need) && (N > 0) && (NBLK <= MAXBLK);

    if (fast) {
        unsigned* glob    = (unsigned*)d_ws;
        unsigned* bases   = (unsigned*)((char*)d_ws + 1024);
        unsigned* payload = (unsigned*)((char*)d_ws + payOff);
        // no memsets: every byte consumed is rewritten every call

        partition_kernel<<<NBLK, BLOCK1, 0, stream>>>(
            bidx, coords, gptr, payload, bases, N);
        glob_kernel<<<1, 256, 0, stream>>>(bases, glob, NBLK, N);
        stats_kernel<<<BUCKETS, BLOCK2, 0, stream>>>(
            payload, bases, glob, (float*)d_out, NBLK, N);
    } else {
        // known-good round-2 path
        int pbShift = 0;
        while ((1 << pbShift) < per_batch) ++pbShift;
        int* glob = (int*)d_ws;
        const size_t accBytes = (size_t)S * sizeof(unsigned);
        unsigned* acc;
        int astride;
        if (ws_size >= accBytes + 64) {
            acc = (unsigned*)((char*)d_ws + 64);
            astride = 1;
            hipMemsetAsync(d_ws, 0, 64 + accBytes, stream);
        } else {
            acc = (unsigned*)d_out;
            astride = 7;
            hipMemsetAsync(d_out, 0, (size_t)out_size * sizeof(float), stream);
            hipMemsetAsync(d_ws, 0, 64, stream);
        }
        int accBlocks = (N + FBLOCK - 1) / FBLOCK;
        if (accBlocks > 2048) accBlocks = 2048;
        accum_kernel<<<accBlocks, FBLOCK, 0, stream>>>(bidx, coords, gptr,
                                                       acc, astride, glob, N);
        const int finBlocks = (S + FBLOCK - 1) / FBLOCK;
        finalize_kernel<<<finBlocks, FBLOCK, 0, stream>>>(acc, astride, glob,
                                                          (float*)d_out, S, pbShift);
    }
}

// Round 10
// 142.161 us; speedup vs baseline: 1.2552x; 1.1787x over previous
//
#include <hip/hip_runtime.h>
#include <hip/hip_bf16.h>

// Round 10: consolidation on the r6 structure (best: 148.6 us) with two fixes.
//
// Algebra (unchanged): voxel = c>>1, u = c&1:
//   norm_center = mu = sum(u)/count, variance = mu*(1-mu),
//   density = count / glob[batch].  Per segment need only packed
//   (count, sum_ux, sum_uy, sum_uz) in one u32.
//
// Evidence ledger: partition ~41 us across 4 designs; direct scatter
// amplifies HBM writes 3.5x (r9: 57 MB for 16 MB payload) -> keep LDS
// sort + coalesced copy-out (r6: 18 MB clean). Global cursor atomics are
// NOT the bottleneck (r8/r9 removed them, no gain). Fixes vs r6:
//  (1) raw payloads cached in LDS during phase A -> phase C re-ranks from
//      LDS instead of re-reading 64 MB of inputs through L2;
//  (2) shfl-up scan (2 barriers) replaces Hillis-Steele (16 barriers).

#define BLOCK1 1024          // partition threads/block
#define PPT 8                // points per thread
#define PTS (BLOCK1 * PPT)   // 8192 points per block
#define BUCKETS 256
#define SEG_SHIFT 12         // log2(SPB)
#define SPB 4096             // segments per bucket; S = BUCKETS*SPB = 2^20
#define BLOCK2 1024          // stats threads/block
#define FBLOCK 256           // fallback path block size

__device__ __forceinline__ unsigned make_pay(int b, int x, int y, int z, int gs) {
    const int seg = (((b * gs + (x >> 1)) * gs + (y >> 1)) * gs) + (z >> 1);
    return ((unsigned)seg << 3) | ((unsigned)(x & 1) << 2)
         | ((unsigned)(y & 1) << 1) | (unsigned)(z & 1);
}

// ---------------- pass 1: partition points into bucket runs ----------------
__global__ __launch_bounds__(BLOCK1, 2)
void partition_kernel(const int* __restrict__ bidx,
                      const int* __restrict__ coords,
                      const int* __restrict__ gptr,
                      unsigned* __restrict__ payload,   // [BUCKETS * CAP]
                      unsigned* __restrict__ g_cursor,  // [BUCKETS]
                      int N, int CAP) {
    __shared__ uint4    s_raw4[PTS / 4];   // 32 KB raw payload cache
    __shared__ unsigned s_pay[PTS];        // 32 KB bucket-sorted payloads
    __shared__ unsigned s_hist[BUCKETS];
    __shared__ unsigned s_base[BUCKETS];   // in-block exclusive offsets
    __shared__ unsigned s_old[BUCKETS];    // reserved global bases
    __shared__ unsigned s_cur[BUCKETS];    // in-block rank cursors
    __shared__ unsigned s_wsum[4];         // per-wave scan totals

    const int tid = threadIdx.x;
    if (tid < BUCKETS) { s_hist[tid] = 0u; s_cur[tid] = 0u; }
    __syncthreads();

    const int gs = gptr[0] >> 1;           // output grid extent (64)
    const int base = blockIdx.x * PTS;
    const int cnt = min(PTS, N - base);

    const int4* __restrict__ bidx4 = (const int4*)bidx;
    const int4* __restrict__ crd4  = (const int4*)coords;

    // ---- phase A: single input read; pay -> LDS raw cache + LDS histogram.
    // Valid payloads are < 2^23, so 0xFFFFFFFF is a safe tail sentinel.
    #pragma unroll
    for (int g = 0; g < PPT / 4; ++g) {
        const int slot = g * BLOCK1 + tid;
        const int p0 = base + slot * 4;
        uint4 r;
        if (p0 + 3 < N) {
            const int q = p0 >> 2;
            const int4 b4 = bidx4[q];
            const int4 c0 = crd4[3 * q + 0];
            const int4 c1 = crd4[3 * q + 1];
            const int4 c2 = crd4[3 * q + 2];
            r.x = make_pay(b4.x, c0.x, c0.y, c0.z, gs);
            r.y = make_pay(b4.y, c0.w, c1.x, c1.y, gs);
            r.z = make_pay(b4.z, c1.z, c1.w, c2.x, gs);
            r.w = make_pay(b4.w, c2.y, c2.z, c2.w, gs);
        } else {
            unsigned t[4];
            #pragma unroll
            for (int j = 0; j < 4; ++j) {
                const int p = p0 + j;
                t[j] = (p < N)
                    ? make_pay(bidx[p], coords[3 * p + 0],
                               coords[3 * p + 1], coords[3 * p + 2], gs)
                    : 0xFFFFFFFFu;
            }
            r.x = t[0]; r.y = t[1]; r.z = t[2]; r.w = t[3];
        }
        s_raw4[slot] = r;                   // ds_write_b128
        if (r.x != 0xFFFFFFFFu) atomicAdd(&s_hist[r.x >> (SEG_SHIFT + 3)], 1u);
        if (r.y != 0xFFFFFFFFu) atomicAdd(&s_hist[r.y >> (SEG_SHIFT + 3)], 1u);
        if (r.z != 0xFFFFFFFFu) atomicAdd(&s_hist[r.z >> (SEG_SHIFT + 3)], 1u);
        if (r.w != 0xFFFFFFFFu) atomicAdd(&s_hist[r.w >> (SEG_SHIFT + 3)], 1u);
    }
    __syncthreads();

    // ---- phase B: shfl-up exclusive scan (2 barriers) + global reservation
    unsigned v = 0u, incl = 0u;
    if (tid < BUCKETS) {
        v = s_hist[tid];
        incl = v;
        #pragma unroll
        for (int d = 1; d < 64; d <<= 1) {
            const unsigned t = __shfl_up(incl, d, 64);
            if ((tid & 63) >= d) incl += t;
        }
        if ((tid & 63) == 63) s_wsum[tid >> 6] = incl;
    }
    __syncthreads();
    if (tid < BUCKETS) {
        const int w = tid >> 6;
        unsigned off = 0u;
        if (w > 0) off += s_wsum[0];
        if (w > 1) off += s_wsum[1];
        if (w > 2) off += s_wsum[2];
        const unsigned ex = incl - v + off;
        s_base[tid] = ex;
        s_old[tid] = atomicAdd(&g_cursor[tid], v);   // 256 atomics/block
    }
    __syncthreads();

    // ---- phase C: re-rank from the LDS raw cache (no global re-read)
    #pragma unroll
    for (int g = 0; g < PPT / 4; ++g) {
        const uint4 r = s_raw4[g * BLOCK1 + tid];    // ds_read_b128
        unsigned bk, rk;
        if (r.x != 0xFFFFFFFFu) {
            bk = r.x >> (SEG_SHIFT + 3);
            rk = atomicAdd(&s_cur[bk], 1u); s_pay[s_base[bk] + rk] = r.x;
        }
        if (r.y != 0xFFFFFFFFu) {
            bk = r.y >> (SEG_SHIFT + 3);
            rk = atomicAdd(&s_cur[bk], 1u); s_pay[s_base[bk] + rk] = r.y;
        }
        if (r.z != 0xFFFFFFFFu) {
            bk = r.z >> (SEG_SHIFT + 3);
            rk = atomicAdd(&s_cur[bk], 1u); s_pay[s_base[bk] + rk] = r.z;
        }
        if (r.w != 0xFFFFFFFFu) {
            bk = r.w >> (SEG_SHIFT + 3);
            rk = atomicAdd(&s_cur[bk], 1u); s_pay[s_base[bk] + rk] = r.w;
        }
    }
    __syncthreads();

    // ---- phase D: coalesced copy-out (runs of ~32 per bucket)
    for (int j = tid; j < cnt; j += BLOCK1) {
        const unsigned p = s_pay[j];
        const unsigned bk = p >> (SEG_SHIFT + 3);
        const unsigned off = s_old[bk] + ((unsigned)j - s_base[bk]);
        if (off < (unsigned)CAP)                     // >15-sigma safety guard
            payload[(size_t)bk * CAP + off] = p;
    }
}

// -------- pass 2: per-bucket LDS accumulation + fused finalize --------
__global__ __launch_bounds__(BLOCK2)
void stats_kernel(const unsigned* __restrict__ payload,
                  const unsigned* __restrict__ g_cursor,
                  float* __restrict__ out, int CAP) {
    __shared__ unsigned fine[SPB];        // 16 KB packed (count,ux,uy,uz)
    __shared__ float s_stage[BLOCK2 * 7]; // 28 KB row staging for coalesced out
    __shared__ unsigned s_g[64];

    const int tid = threadIdx.x;
    const int k = blockIdx.x;

    for (int s = tid; s < SPB; s += BLOCK2) fine[s] = 0u;
    if (tid < 64) s_g[tid] = g_cursor[(k & ~63) + tid];   // 64 buckets/batch
    __syncthreads();
    for (int o = 32; o > 0; o >>= 1) {
        if (tid < o) s_g[tid] += s_g[tid + o];
        __syncthreads();
    }
    const float ginv = 1.0f / (float)s_g[0];   // glob[batch]; unused if empty

    unsigned cnt = g_cursor[k];
    if (cnt > (unsigned)CAP) cnt = (unsigned)CAP;
    const uint4* __restrict__ pay4 = (const uint4*)(payload + (size_t)k * CAP);
    const unsigned n4 = cnt >> 2;

    for (unsigned j = tid; j < n4; j += BLOCK2) {
        const uint4 p = pay4[j];
        atomicAdd(&fine[(p.x >> 3) & (SPB - 1)],
                  (1u << 24) | ((p.x & 4u) << 14) | ((p.x & 2u) << 7) | (p.x & 1u));
        atomicAdd(&fine[(p.y >> 3) & (SPB - 1)],
                  (1u << 24) | ((p.y & 4u) << 14) | ((p.y & 2u) << 7) | (p.y & 1u));
        atomicAdd(&fine[(p.z >> 3) & (SPB - 1)],
                  (1u << 24) | ((p.z & 4u) << 14) | ((p.z & 2u) << 7) | (p.z & 1u));
        atomicAdd(&fine[(p.w >> 3) & (SPB - 1)],
                  (1u << 24) | ((p.w & 4u) << 14) | ((p.w & 2u) << 7) | (p.w & 1u));
    }
    for (unsigned j = (n4 << 2) + tid; j < cnt; j += BLOCK2) {
        const unsigned p = payload[(size_t)k * CAP + j];
        atomicAdd(&fine[(p >> 3) & (SPB - 1)],
                  (1u << 24) | ((p & 4u) << 14) | ((p & 2u) << 7) | (p & 1u));
    }
    __syncthreads();

    // finalize in 4 tiles of 1024 rows: compute -> LDS stage -> float4 out
    for (int t = 0; t < SPB; t += BLOCK2) {
        const unsigned a = fine[t + tid];
        const int c = (int)(a >> 24);
        float d0 = 0.f, vx = 0.f, vy = 0.f, vz = 0.f, mx = 0.f, my = 0.f, mz = 0.f;
        if (c > 0) {
            const float inv = 1.0f / (float)c;
            mx = (float)((a >> 16) & 0xffu) * inv;
            my = (float)((a >> 8) & 0xffu) * inv;
            mz = (float)(a & 0xffu) * inv;
            vx = mx - mx * mx;
            vy = my - my * my;
            vz = mz - mz * mz;
            d0 = (float)c * ginv;
        }
        float* st = &s_stage[tid * 7];
        st[0] = d0;
        st[1] = vx; st[2] = vy; st[3] = vz;
        st[4] = mx; st[5] = my; st[6] = mz;
        __syncthreads();

        const float4* src = (const float4*)s_stage;
        float4* dst = (float4*)(out + ((size_t)k * SPB + t) * 7);
        #pragma unroll
        for (int j = 0; j < 2; ++j) {
            const int idx = j * BLOCK2 + tid;
            if (idx < (BLOCK2 * 7) / 4) dst[idx] = src[idx];
        }
        __syncthreads();
    }
}

// ---------------- fallback (round-2 path, known-good) ----------------
__global__ __launch_bounds__(FBLOCK)
void accum_kernel(const int* __restrict__ bidx,
                  const int* __restrict__ coords,
                  const int* __restrict__ gptr,
                  unsigned* __restrict__ acc, int astride,
                  int* __restrict__ glob, int N) {
    __shared__ int gcnt[4];
    if (threadIdx.x < 4) gcnt[threadIdx.x] = 0;
    __syncthreads();
    const int gs = gptr[0] >> 1;
    int l0 = 0, l1 = 0, l2 = 0, l3 = 0;
    const int stride = gridDim.x * blockDim.x;
    for (int i = blockIdx.x * blockDim.x + threadIdx.x; i < N; i += stride) {
        const int b  = bidx[i];
        const int cx = coords[3 * i + 0];
        const int cy = coords[3 * i + 1];
        const int cz = coords[3 * i + 2];
        const int seg = (((b * gs + (cx >> 1)) * gs + (cy >> 1)) * gs) + (cz >> 1);
        const unsigned val = (1u << 24)
                           | ((unsigned)(cx & 1) << 16)
                           | ((unsigned)(cy & 1) << 8)
                           |  (unsigned)(cz & 1);
        atomicAdd(&acc[(size_t)seg * astride], val);
        l0 += (b == 0); l1 += (b == 1); l2 += (b == 2); l3 += (b == 3);
    }
    if (l0) atomicAdd(&gcnt[0], l0);
    if (l1) atomicAdd(&gcnt[1], l1);
    if (l2) atomicAdd(&gcnt[2], l2);
    if (l3) atomicAdd(&gcnt[3], l3);
    __syncthreads();
    if (threadIdx.x < 4 && gcnt[threadIdx.x] != 0)
        atomicAdd(&glob[threadIdx.x], gcnt[threadIdx.x]);
}

__global__ __launch_bounds__(FBLOCK)
void finalize_kernel(const unsigned* __restrict__ acc, int astride,
                     const int* __restrict__ glob,
                     float* __restrict__ out, int S, int pbShift) {
    const int s = blockIdx.x * blockDim.x + threadIdx.x;
    if (s >= S) return;
    const unsigned a = acc[(size_t)s * astride];
    const int b = s >> pbShift;
    const int c = (int)(a >> 24);
    float d0 = 0.f, vx = 0.f, vy = 0.f, vz = 0.f, mx = 0.f, my = 0.f, mz = 0.f;
    if (c > 0) {
        const float inv = 1.0f / (float)c;
        mx = (float)((a >> 16) & 0xffu) * inv;
        my = (float)((a >> 8) & 0xffu) * inv;
        mz = (float)(a & 0xffu) * inv;
        vx = mx - mx * mx; vy = my - my * my; vz = mz - mz * mz;
        d0 = (float)c / (float)glob[b];
    }
    float* row = out + (size_t)s * 7;
    row[0] = d0;
    row[1] = vx; row[2] = vy; row[3] = vz;
    row[4] = mx; row[5] = my; row[6] = mz;
}

extern "C" void kernel_launch(void* const* d_in, const int* in_sizes, int n_in,
                              void* d_out, int out_size, void* d_ws, size_t ws_size,
                              hipStream_t stream) {
    const int* bidx   = (const int*)d_in[1];   // batch_idx [N]
    const int* coords = (const int*)d_in[2];   // coords [N,3]
    const int* gptr   = (const int*)d_in[3];   // grid_size scalar (128)

    const int N = in_sizes[1];
    const int S = out_size / 7;                // 1,048,576
    const int per_batch = S / 4;               // B = 4

    const int NpB = (N + BUCKETS - 1) / BUCKETS;
    const int CAP = ((NpB + NpB / 8 + 64) + 63) & ~63;   // ~+15 sigma headroom
    const size_t need = 1024 + (size_t)BUCKETS * (size_t)CAP * 4u;

    const bool fast = (S == (BUCKETS * SPB)) && (per_batch / SPB == 64) &&
                      (ws_size >= need) && (N > 0);

    if (fast) {
        unsigned* g_cursor = (unsigned*)d_ws;                 // 1 KB
        unsigned* payload  = (unsigned*)((char*)d_ws + 1024); // 256*CAP u32
        hipMemsetAsync(d_ws, 0, 1024, stream);

        const int blocks = (N + PTS - 1) / PTS;               // 489
        partition_kernel<<<blocks, BLOCK1, 0, stream>>>(
            bidx, coords, gptr, payload, g_cursor, N, CAP);
        stats_kernel<<<BUCKETS, BLOCK2, 0, stream>>>(
            payload, g_cursor, (float*)d_out, CAP);
    } else {
        // known-good round-2 path
        int pbShift = 0;
        while ((1 << pbShift) < per_batch) ++pbShift;
        int* glob = (int*)d_ws;
        const size_t accBytes = (size_t)S * sizeof(unsigned);
        unsigned* acc;
        int astride;
        if (ws_size >= accBytes + 64) {
            acc = (unsigned*)((char*)d_ws + 64);
            astride = 1;
            hipMemsetAsync(d_ws, 0, 64 + accBytes, stream);
        } else {
            acc = (unsigned*)d_out;
            astride = 7;
            hipMemsetAsync(d_out, 0, (size_t)out_size * sizeof(float), stream);
            hipMemsetAsync(d_ws, 0, 64, stream);
        }
        int accBlocks = (N + FBLOCK - 1) / FBLOCK;
        if (accBlocks > 2048) accBlocks = 2048;
        accum_kernel<<<accBlocks, FBLOCK, 0, stream>>>(bidx, coords, gptr,
                                                       acc, astride, glob, N);
        const int finBlocks = (S + FBLOCK - 1) / FBLOCK;
        finalize_kernel<<<finBlocks, FBLOCK, 0, stream>>>(acc, astride, glob,
                                                          (float*)d_out, S, pbShift);
    }
}